// Round 2
// baseline (610.658 us; speedup 1.0000x reference)
//
#include <hip/hip_runtime.h>

#define N_INST 100
#define HW_PIX 819200
#define NPAIR (N_INST * N_INST)

struct alignas(16) Ent { int p; int ab; float ra; float rb; };

// K0: argsort(cls_prob) descending (f32, distinct w.p. 1; tie-break by larger
// original index first == jnp stable-ascending reversed).
__global__ __launch_bounds__(128) void k0_sort(
    const float* __restrict__ cls_prob,
    const int* __restrict__ cls_idx,
    int* __restrict__ order,
    int* __restrict__ cls_sorted,
    float* __restrict__ out_order) {
  __shared__ float v[N_INST];
  __shared__ int ordl[N_INST];
  int t = threadIdx.x;
  if (t < N_INST) v[t] = cls_prob[t];
  __syncthreads();
  if (t < N_INST) {
    float mv = v[t];
    int r = 0;
    for (int j = 0; j < N_INST; ++j) {
      float vj = v[j];
      r += (vj > mv) || (vj == mv && j > t);
    }
    ordl[r] = t;
  }
  __syncthreads();
  if (t < N_INST) {
    int o = ordl[t];
    order[t] = o;
    cls_sorted[t] = cls_idx[o];
    out_order[t] = (float)o;  // ints <= 99 exact in f32
  }
}

// K1: per-pixel softmax over 100 sorted instances (np-exact: max-subtract,
// sequential f32 sum in sorted-row order). At most 2 can be >= 0.4. Rare
// candidates appended to a global list; masksum/paircnt via global atomics.
__global__ __launch_bounds__(256) void k1_cand(
    const float* __restrict__ mp,
    const int* __restrict__ order,
    unsigned int* __restrict__ masksum,
    unsigned int* __restrict__ paircnt,
    unsigned int* __restrict__ nc,
    Ent* __restrict__ list) {
  int p = blockIdx.x * 256 + threadIdx.x;
  float x[N_INST];
#pragma unroll
  for (int k = 0; k < N_INST; ++k)
    x[k] = mp[(size_t)order[k] * HW_PIX + p];
  float m = x[0];
#pragma unroll
  for (int k = 1; k < N_INST; ++k) m = fmaxf(m, x[k]);
  float denom = 0.0f, e1 = -1.0f, e2 = -1.0f, r1 = 0.0f, r2 = 0.0f;
  int s1 = 0, s2 = 0;
#pragma unroll
  for (int k = 0; k < N_INST; ++k) {
    float e = expf(x[k] - m);  // precise expf, matches np f32 semantics ~1ulp
    denom += e;                 // sequential order 0..99 like np axis-0 reduce
    if (e > e1)      { e2 = e1; s2 = s1; r2 = r1; e1 = e; s1 = k; r1 = x[k]; }
    else if (e > e2) { e2 = e;  s2 = k;  r2 = x[k]; }
  }
  bool c1 = (e1 / denom) >= 0.4f;  // true f32 division like np softmax
  bool c2 = (e2 / denom) >= 0.4f;  // c2 implies c1 (e1 >= e2)
  if (c1) {
    int a = s1, b = 255;
    float ra = r1, rb = 0.0f;
    atomicAdd(&masksum[s1], 1u);
    if (c2) {
      atomicAdd(&masksum[s2], 1u);
      if (s2 < s1) { a = s2; ra = r2; b = s1; rb = r1; }
      else         { b = s2; rb = r2; }
      atomicAdd(&paircnt[a * N_INST + b], 1u);
    }
    unsigned idx = atomicAdd(nc, 1u);
    Ent e; e.p = p; e.ab = a | (b << 8); e.ra = ra; e.rb = rb;
    list[idx] = e;
  }
}

// K2: sequential greedy keep, one block. overlap_s = sum over earlier kept
// same-class j of paircnt[j][s] (valid because a pixel has <=2 candidates,
// so mimg[c] at a pixel is set iff the pixel's other candidate was kept).
__global__ __launch_bounds__(256) void k2_keep(
    const unsigned int* __restrict__ paircnt,
    const unsigned int* __restrict__ masksum,
    const int* __restrict__ cls_sorted,
    unsigned long long* __restrict__ keepmask,
    float* __restrict__ out_keep) {
  __shared__ unsigned int pl[NPAIR];
  __shared__ unsigned int ms[N_INST];
  __shared__ int cl[N_INST];
  for (int i = threadIdx.x; i < NPAIR; i += 256) pl[i] = paircnt[i];
  if (threadIdx.x < N_INST) {
    ms[threadIdx.x] = masksum[threadIdx.x];
    cl[threadIdx.x] = cls_sorted[threadIdx.x];
  }
  __syncthreads();
  if (threadIdx.x < 64) {
    int l = threadIdx.x;
    int j2 = l + 64;
    int cA = cl[l];
    int cB = (j2 < N_INST) ? cl[j2] : -1;
    bool kA = false, kB = false;
    unsigned long long km0 = 0, km1 = 0;
    for (int s = 0; s < N_INST; ++s) {
      int cs = cl[s];
      unsigned int ov = 0;
      if (l < s && kA && cA == cs) ov += pl[l * N_INST + s];
      if (j2 < s && kB && cB == cs) ov += pl[j2 * N_INST + s];
#pragma unroll
      for (int off = 32; off >= 1; off >>= 1) ov += __shfl_xor((int)ov, off);
      unsigned int m_s = ms[s];
      float overlap = (float)ov / fmaxf((float)m_s, 1.0f);
      bool keep = (m_s > 0u) && (m_s < (unsigned)HW_PIX) && (overlap <= 0.03f);
      if (keep) { if (s < 64) km0 |= 1ull << s; else km1 |= 1ull << (s - 64); }
      if (s == l)  kA = keep;
      if (s == j2) kB = keep;
    }
    if (l == 0) { keepmask[0] = km0; keepmask[1] = km1; }
    out_keep[l] = kA ? 1.0f : 0.0f;
    if (j2 < N_INST) out_keep[j2] = kB ? 1.0f : 0.0f;
  }
}

// K3: sparse scatter of kept candidate pixels onto the pre-zeroed output.
__global__ __launch_bounds__(256) void k3_scatter(
    const unsigned int* __restrict__ nc,
    const Ent* __restrict__ list,
    const unsigned long long* __restrict__ keepmask,
    float* __restrict__ out_masks) {
  unsigned long long km0 = keepmask[0], km1 = keepmask[1];
  unsigned n = *nc;
  for (unsigned i = blockIdx.x * 256 + threadIdx.x; i < n; i += gridDim.x * 256) {
    Ent e = list[i];
    int a = e.ab & 0xFF;
    int b = (e.ab >> 8) & 0xFF;
    bool ka = (a < 64) ? (((km0 >> a) & 1ull) != 0)
                       : ((a < N_INST) && (((km1 >> (a - 64)) & 1ull) != 0));
    bool kb = (b < 64) ? (((km0 >> b) & 1ull) != 0)
                       : ((b < N_INST) && (((km1 >> (b - 64)) & 1ull) != 0));
    if (ka)      out_masks[(size_t)a * HW_PIX + e.p] = e.ra;
    else if (kb) out_masks[(size_t)b * HW_PIX + e.p] = e.rb;
  }
}

extern "C" void kernel_launch(void* const* d_in, const int* in_sizes, int n_in,
                              void* d_out, int out_size, void* d_ws, size_t ws_size,
                              hipStream_t stream) {
  const float* cls_prob = (const float*)d_in[0];
  const float* mp       = (const float*)d_in[1];
  const int*   cls_idx  = (const int*)d_in[2];
  float* out = (float*)d_out;

  char* ws = (char*)d_ws;
  int* order                   = (int*)(ws + 0);       // 400 B
  int* cls_sorted              = (int*)(ws + 400);     // 400 B
  unsigned long long* keepmask = (unsigned long long*)(ws + 800);  // 16 B
  unsigned int* nc             = (unsigned int*)(ws + 1024);       // 4 B
  unsigned int* masksum        = (unsigned int*)(ws + 2048);       // 400 B
  unsigned int* paircnt        = (unsigned int*)(ws + 4096);       // 40 KB
  Ent* list                    = (Ent*)(ws + 65536);   // up to 13.1 MB worst case

  // output layout (f32): keep[100] | kept_masks[100*HW] | order[100]
  float* out_keep  = out;
  float* out_masks = out + N_INST;
  float* out_order = out + N_INST + (size_t)N_INST * HW_PIX;

  // Zero accumulators (ws poisoned 0xAA) and the kept_masks output region.
  hipMemsetAsync(ws + 1024, 0, 4096 - 1024 + 40000, stream);
  hipMemsetAsync(out_masks, 0, (size_t)N_INST * HW_PIX * sizeof(float), stream);

  k0_sort<<<1, 128, 0, stream>>>(cls_prob, cls_idx, order, cls_sorted, out_order);
  k1_cand<<<HW_PIX / 256, 256, 0, stream>>>(mp, order, masksum, paircnt, nc, list);
  k2_keep<<<1, 256, 0, stream>>>(paircnt, masksum, cls_sorted, keepmask, out_keep);
  k3_scatter<<<128, 256, 0, stream>>>(nc, list, keepmask, out_masks);
}